// Round 4
// baseline (1656.887 us; speedup 1.0000x reference)
//
#include <hip/hip_runtime.h>

typedef __attribute__((ext_vector_type(8))) short short8;
typedef __attribute__((ext_vector_type(16))) float f32x16;
typedef __attribute__((ext_vector_type(2))) unsigned int u32x2;
typedef __attribute__((ext_vector_type(2))) unsigned long long u64x2;
typedef unsigned short u16;
typedef unsigned int u32;
typedef unsigned long long u64;

#define B_ROWS 4096
#define D_KEYS 50000
#define DPAD   50048
#define KDIM   64
#define NCOL   1000
#define NPAD   1024
#define SCALEF 300000.0f
#define EPSF   1e-4f
#define NCHUNKS 782          // DPAD/64
#define NEG2S  (-2.0f / SCALEF)

// ---------------- helpers ----------------

__device__ __forceinline__ u16 f2bf(float f) {          // RNE float->bf16
    u32 u = __builtin_bit_cast(u32, f);
    u = (u + 0x7FFFu + ((u >> 16) & 1u)) >> 16;
    return (u16)u;
}

__device__ __forceinline__ u32 pack2(float a, float b) { // 2xf32 -> packed bf16x2
    return (u32)f2bf(a) | ((u32)f2bf(b) << 16);
}

__device__ __forceinline__ void glds16(const void* g, void* l) {
    __builtin_amdgcn_global_load_lds(
        (const __attribute__((address_space(1))) u32*)(uintptr_t)g,
        (__attribute__((address_space(3))) u32*)(uintptr_t)l, 16, 0, 0);
}

// ---------------- pre-pass kernels ----------------

__global__ void prep_x_kernel(const float* __restrict__ x,
                              u16* __restrict__ x_bf, float* __restrict__ xn2) {
    int row = (blockIdx.x * blockDim.x + threadIdx.x) >> 6;
    int lane = threadIdx.x & 63;
    if (row >= B_ROWS) return;
    float v = x[(size_t)row * KDIM + lane];
    x_bf[(size_t)row * KDIM + lane] = f2bf(v);
    float s = v * v;
    #pragma unroll
    for (int off = 32; off > 0; off >>= 1) s += __shfl_down(s, off, 64);
    if (lane == 0) xn2[row] = s * (1.0f / SCALEF);
}

__global__ void prep_keys_kernel(const float* __restrict__ keys,
                                 u16* __restrict__ keys_bf, float* __restrict__ kn2) {
    int row = (blockIdx.x * blockDim.x + threadIdx.x) >> 6;
    int lane = threadIdx.x & 63;
    if (row >= DPAD) return;
    float v = (row < D_KEYS) ? keys[(size_t)row * KDIM + lane] : 0.f;
    keys_bf[(size_t)row * KDIM + lane] = f2bf(v);
    float s = v * v;
    #pragma unroll
    for (int off = 32; off > 0; off >>= 1) s += __shfl_down(s, off, 64);
    if (lane == 0) kn2[row] = s * (1.0f / SCALEF) + EPSF;
}

// V (50000x1000 f32) -> Vt (1024x50048 bf16, d contiguous), zero-padded, u32 writes
__global__ void prep_v_kernel(const float* __restrict__ V, u16* __restrict__ vt) {
    __shared__ float tile[64][65];
    const int d0 = blockIdx.x * 64;
    const int n0 = blockIdx.y * 64;
    const int t = threadIdx.x;
    #pragma unroll
    for (int p = 0; p < 16; p++) {
        int idx = p * 256 + t;
        int di = idx >> 6, nj = idx & 63;
        int d = d0 + di, n = n0 + nj;
        tile[di][nj] = (d < D_KEYS && n < NCOL) ? V[(size_t)d * NCOL + n] : 0.f;
    }
    __syncthreads();
    #pragma unroll
    for (int p = 0; p < 8; p++) {
        int idx = p * 256 + t;
        int ni = idx >> 5, dp = idx & 31;          // d-pair
        u32 pk = pack2(tile[2 * dp][ni], tile[2 * dp + 1][ni]);
        *(u32*)&vt[(size_t)(n0 + ni) * DPAD + d0 + 2 * dp] = pk;
    }
}

__global__ void zero_kernel(float4* __restrict__ p, int n4) {
    for (int i = blockIdx.x * 256 + threadIdx.x; i < n4; i += gridDim.x * 256)
        p[i] = make_float4(0.f, 0.f, 0.f, 0.f);
}

// ---------------- main MFMA kernel ----------------
// grid (8 n-tiles, 16 b-tiles, 4 d-splits), 256 threads (4 waves)
// BM=256 (wave: 2 m-strips of 32), BN=128 (4 n-tiles of 32), D-chunk 64.
__global__ __launch_bounds__(256, 2)
void varkeys_mfma2_kernel(const u16* __restrict__ x_bf,
                          const u16* __restrict__ keys_bf,
                          const u16* __restrict__ vt_bf,
                          const float* __restrict__ xn2,
                          const float* __restrict__ kn2,
                          float* __restrict__ partial,
                          int atomic_mode) {
    __shared__ alignas(16) u16 keys_lds[64 * 64];    // [d][k]
    __shared__ alignas(16) u16 v_lds[128 * 64];      // [n][d]
    __shared__ alignas(16) u16 ker_lds[256 * 64];    // [b][d], 8B-swizzled
    __shared__ alignas(16) float kn_lds[64];

    const int t = threadIdx.x;
    const int w = t >> 6;
    const int lane = t & 63;
    const int half = lane >> 5;
    const int l31 = lane & 31;

    const int n0 = blockIdx.x * 128;
    const int b0 = blockIdx.y * 256;
    const int bz = blockIdx.z;
    const int c_begin = (bz * NCHUNKS) >> 2;
    const int c_end = ((bz + 1) * NCHUNKS) >> 2;

    const int bl0 = 32 * w + l31;          // strip-0 local b row
    const int bl1 = 128 + bl0;             // strip-1
    const float xnv0 = xn2[b0 + bl0];
    const float xnv1 = xn2[b0 + bl1];

    // x fragments (scores B operand) pinned in VGPRs: [strip][kchunk]
    short8 xfrag[2][4];
    #pragma unroll
    for (int s = 0; s < 2; s++)
        #pragma unroll
        for (int kk = 0; kk < 4; kk++)
            xfrag[s][kk] = *(const short8*)(x_bf + (size_t)(b0 + 128 * s + bl0) * KDIM
                                            + kk * 16 + half * 8);

    f32x16 acc[2][4];
    #pragma unroll
    for (int mt = 0; mt < 2; mt++)
        #pragma unroll
        for (int nt = 0; nt < 4; nt++)
            #pragma unroll
            for (int i = 0; i < 16; i++) acc[mt][nt][i] = 0.f;

    const int srow = lane >> 3;
    const int cg = (lane & 7) ^ srow;      // swizzled 16B chunk for staging

    u64* kerp = (u64*)ker_lds;
    const int swz0 = bl0 & 15, swz1 = bl1 & 15;

    for (int c = c_begin; c < c_end; c++) {
        const int d0 = c * 64;

        // ---- stage keys (8KB) + Vt (16KB), 16B-swizzled direct-to-LDS ----
        #pragma unroll
        for (int q = 0; q < 2; q++) {
            int i = w * 2 + q;
            glds16(keys_bf + (size_t)(d0 + 8 * i + srow) * KDIM + cg * 8,
                   &keys_lds[i * 512]);
        }
        #pragma unroll
        for (int q = 0; q < 4; q++) {
            int i = w * 4 + q;
            glds16(vt_bf + (size_t)(n0 + 8 * i + srow) * DPAD + d0 + cg * 8,
                   &v_lds[i * 512]);
        }
        if (t < 16) *(float4*)&kn_lds[t * 4] = *(const float4*)&kn2[d0 + t * 4];
        __syncthreads();

        const bool tail = (d0 + 64 > D_KEYS);

        // ---- scores: ker[d(64) x b(256)]; each wave handles its 2 b-strips ----
        #pragma unroll
        for (int dt = 0; dt < 2; dt++) {
            f32x16 s0, s1;
            #pragma unroll
            for (int i = 0; i < 16; i++) { s0[i] = 0.f; s1[i] = 0.f; }
            const int dl = dt * 32 + l31;
            #pragma unroll
            for (int kk = 0; kk < 4; kk++) {
                int cidx = kk * 2 + half;
                short8 af = *(const short8*)&keys_lds[dl * 64 + ((cidx ^ (dl & 7)) * 8)];
                s0 = __builtin_amdgcn_mfma_f32_32x32x16_bf16(af, xfrag[0][kk], s0, 0, 0, 0);
                s1 = __builtin_amdgcn_mfma_f32_32x32x16_bf16(af, xfrag[1][kk], s1, 0, 0, 0);
            }
            // epilogue for both strips: dist -> rcp -> bf16, ds_write_b64 swizzled
            #pragma unroll
            for (int strip = 0; strip < 2; strip++) {
                const f32x16& s = strip ? s1 : s0;
                const float xnv = strip ? xnv1 : xnv0;
                const int bl = strip ? bl1 : bl0;
                const int swz = strip ? swz1 : swz0;
                #pragma unroll
                for (int q = 0; q < 4; q++) {
                    float kv[4];
                    #pragma unroll
                    for (int j = 0; j < 4; j++) {
                        int r = 4 * q + j;
                        int dloc = dt * 32 + 8 * q + 4 * half + j;
                        float dist = fmaf(s[r], NEG2S, kn_lds[dloc] + xnv);
                        kv[j] = __builtin_amdgcn_rcpf(dist);
                    }
                    if (tail) {
                        #pragma unroll
                        for (int j = 0; j < 4; j++)
                            if (d0 + dt * 32 + 8 * q + 4 * half + j >= D_KEYS) kv[j] = 0.f;
                    }
                    u32x2 pk;
                    pk.x = pack2(kv[0], kv[1]);
                    pk.y = pack2(kv[2], kv[3]);
                    int gcol = dt * 8 + 2 * q + half;
                    kerp[bl * 16 + (gcol ^ swz)] = __builtin_bit_cast(u64, pk);
                }
            }
        }
        // no barrier: each wave reads back only ker rows it wrote (lgkmcnt-ordered)

        // ---- PV: acc[2 strips][4 nt] += ker(A) x Vt(B) ----
        #pragma unroll
        for (int kc = 0; kc < 4; kc++) {
            const int g0 = 4 * kc + 2 * half;
            u64x2 k0v, k1v;
            k0v.x = kerp[bl0 * 16 + (g0 ^ swz0)];
            k0v.y = kerp[bl0 * 16 + ((g0 + 1) ^ swz0)];
            k1v.x = kerp[bl1 * 16 + (g0 ^ swz1)];
            k1v.y = kerp[bl1 * 16 + ((g0 + 1) ^ swz1)];
            short8 kf0 = __builtin_bit_cast(short8, k0v);
            short8 kf1 = __builtin_bit_cast(short8, k1v);
            const int cidx = kc * 2 + half;
            #pragma unroll
            for (int nt = 0; nt < 4; nt++) {
                int nl = nt * 32 + l31;
                short8 vf = *(const short8*)&v_lds[nl * 64 + ((cidx ^ (nl & 7)) * 8)];
                acc[0][nt] = __builtin_amdgcn_mfma_f32_32x32x16_bf16(kf0, vf, acc[0][nt], 0, 0, 0);
                acc[1][nt] = __builtin_amdgcn_mfma_f32_32x32x16_bf16(kf1, vf, acc[1][nt], 0, 0, 0);
            }
        }
        __syncthreads();   // protect keys_lds/v_lds before next stage
    }

    // ---- output: per-dz partial buffer, or atomicAdd into shared partial ----
    float* pout = atomic_mode ? partial
                              : partial + (size_t)bz * B_ROWS * NCOL;
    #pragma unroll
    for (int mt = 0; mt < 2; mt++) {
        #pragma unroll
        for (int nt = 0; nt < 4; nt++) {
            int n = n0 + nt * 32 + l31;
            if (n < NCOL) {
                #pragma unroll
                for (int r = 0; r < 16; r++) {
                    int brow = b0 + mt * 128 + 32 * w + (r & 3) + 8 * (r >> 2) + 4 * half;
                    if (atomic_mode)
                        atomicAdd(&pout[(size_t)brow * NCOL + n], acc[mt][nt][r]);
                    else
                        pout[(size_t)brow * NCOL + n] = acc[mt][nt][r];
                }
            }
        }
    }
}

// sum pcount partials, row-normalize
__global__ void finish_kernel(const float* __restrict__ partial, float* __restrict__ out,
                              int pcount) {
    const int b = blockIdx.x;
    const int t = threadIdx.x;
    float s = 0.f;
    for (int n = t; n < NCOL; n += 256) {
        float v = 0.f;
        for (int p = 0; p < pcount; p++)
            v += partial[(size_t)p * B_ROWS * NCOL + (size_t)b * NCOL + n];
        s += v;
    }
    __shared__ float red[4];
    #pragma unroll
    for (int off = 32; off > 0; off >>= 1) s += __shfl_down(s, off, 64);
    if ((t & 63) == 0) red[t >> 6] = s;
    __syncthreads();
    float inv = 1.0f / (red[0] + red[1] + red[2] + red[3]);
    for (int n = t; n < NCOL; n += 256) {
        float v = 0.f;
        for (int p = 0; p < pcount; p++)
            v += partial[(size_t)p * B_ROWS * NCOL + (size_t)b * NCOL + n];
        out[(size_t)b * NCOL + n] = v * inv;
    }
}

// ================= fallback fp32 path (round-1, known-correct) =================

__global__ void row_norm2_kernel(const float* __restrict__ a,
                                 float* __restrict__ out, int rows) {
    int wave = (blockIdx.x * blockDim.x + threadIdx.x) >> 6;
    int lane = threadIdx.x & 63;
    if (wave >= rows) return;
    float v = a[(size_t)wave * KDIM + lane];
    float s = v * v;
    #pragma unroll
    for (int off = 32; off > 0; off >>= 1) s += __shfl_down(s, off, 64);
    if (lane == 0) out[wave] = s;
}

#define DC 64
#define BT 64
#define NT 256

__global__ __launch_bounds__(256, 1)
void varkeys_main_kernel(const float* __restrict__ x,
                         const float* __restrict__ keys,
                         const float* __restrict__ V,
                         const float* __restrict__ xn,
                         const float* __restrict__ kn,
                         float* __restrict__ out) {
    __shared__ float x_lds[BT][68];
    __shared__ float keys_lds[DC][68];
    __shared__ float ker_lds[DC][65];
    __shared__ float xn_lds[BT];
    __shared__ float kn_lds[DC];
    const int t = threadIdx.x;
    const int n0 = blockIdx.x * NT;
    const int b0 = blockIdx.y * BT;
    for (int q = t; q < BT * 16; q += 256) {
        int row = q >> 4, c4 = q & 15;
        float4 v = *(const float4*)(x + (size_t)(b0 + row) * KDIM + c4 * 4);
        *(float4*)&x_lds[row][c4 * 4] = v;
    }
    if (t < BT) xn_lds[t] = xn[b0 + t];
    const int tn = t & 63;
    const int tb = t >> 6;
    const int tb16 = tb * 16;
    const int n4 = n0 + 4 * tn;
    const bool nvalid = (n4 < NCOL);
    float4 acc[16];
    #pragma unroll
    for (int j = 0; j < 16; j++) acc[j] = make_float4(0.f, 0.f, 0.f, 0.f);
    const int td = t & 15;
    const int tq = t >> 4;
    for (int d0 = 0; d0 < D_KEYS; d0 += DC) {
        const int dlim = min(DC, D_KEYS - d0);
        for (int q = t; q < DC * 16; q += 256) {
            int row = q >> 4, c4 = q & 15;
            if (d0 + row < D_KEYS) {
                float4 v = *(const float4*)(keys + (size_t)(d0 + row) * KDIM + c4 * 4);
                *(float4*)&keys_lds[row][c4 * 4] = v;
            }
        }
        if (t < DC) kn_lds[t] = (d0 + t < D_KEYS) ? kn[d0 + t] : 0.f;
        __syncthreads();
        {
            float4 s[4][4];
            #pragma unroll
            for (int i = 0; i < 4; i++)
                #pragma unroll
                for (int j = 0; j < 4; j++) s[i][j] = make_float4(0.f, 0.f, 0.f, 0.f);
            #pragma unroll
            for (int k4 = 0; k4 < 16; k4++) {
                float4 kv[4], xv[4];
                #pragma unroll
                for (int i = 0; i < 4; i++) kv[i] = *(const float4*)&keys_lds[td + 16 * i][k4 * 4];
                #pragma unroll
                for (int j = 0; j < 4; j++) xv[j] = *(const float4*)&x_lds[tq + 16 * j][k4 * 4];
                #pragma unroll
                for (int i = 0; i < 4; i++)
                    #pragma unroll
                    for (int j = 0; j < 4; j++) {
                        s[i][j].x += kv[i].x * xv[j].x;
                        s[i][j].y += kv[i].y * xv[j].y;
                        s[i][j].z += kv[i].z * xv[j].z;
                        s[i][j].w += kv[i].w * xv[j].w;
                    }
            }
            #pragma unroll
            for (int i = 0; i < 4; i++)
                #pragma unroll
                for (int j = 0; j < 4; j++) {
                    int d = td + 16 * i, bb = tq + 16 * j;
                    float dot = s[i][j].x + s[i][j].y + s[i][j].z + s[i][j].w;
                    float dist = (kn_lds[d] - 2.0f * dot + xn_lds[bb]) * (1.0f / SCALEF) + EPSF;
                    ker_lds[d][bb] = 1.0f / dist;
                }
        }
        __syncthreads();
        if (nvalid) {
            const float* vp = V + (size_t)d0 * NCOL + n4;
            for (int d = 0; d < dlim; d += 4) {
                float4 v0 = *(const float4*)(vp + (size_t)(d + 0) * NCOL);
                float4 v1 = *(const float4*)(vp + (size_t)(d + 1) * NCOL);
                float4 v2 = *(const float4*)(vp + (size_t)(d + 2) * NCOL);
                float4 v3 = *(const float4*)(vp + (size_t)(d + 3) * NCOL);
                #pragma unroll
                for (int j = 0; j < 16; j++) {
                    float k0 = ker_lds[d + 0][tb16 + j];
                    float k1 = ker_lds[d + 1][tb16 + j];
                    float k2 = ker_lds[d + 2][tb16 + j];
                    float k3 = ker_lds[d + 3][tb16 + j];
                    acc[j].x += k0 * v0.x + k1 * v1.x + k2 * v2.x + k3 * v3.x;
                    acc[j].y += k0 * v0.y + k1 * v1.y + k2 * v2.y + k3 * v3.y;
                    acc[j].z += k0 * v0.z + k1 * v1.z + k2 * v2.z + k3 * v3.z;
                    acc[j].w += k0 * v0.w + k1 * v1.w + k2 * v2.w + k3 * v3.w;
                }
            }
        }
    }
    if (nvalid) {
        #pragma unroll
        for (int j = 0; j < 16; j++) {
            int b = b0 + tb16 + j;
            *(float4*)(out + (size_t)b * NCOL + n4) = acc[j];
        }
    }
}

__global__ void normalize_kernel(float* __restrict__ out) {
    const int b = blockIdx.x;
    float* row = out + (size_t)b * NCOL;
    const int t = threadIdx.x;
    float s = 0.f;
    for (int n = t; n < NCOL; n += 256) s += row[n];
    __shared__ float red[4];
    #pragma unroll
    for (int off = 32; off > 0; off >>= 1) s += __shfl_down(s, off, 64);
    if ((t & 63) == 0) red[t >> 6] = s;
    __syncthreads();
    float inv = 1.0f / (red[0] + red[1] + red[2] + red[3]);
    for (int n = t; n < NCOL; n += 256) row[n] *= inv;
}

// ================= launch =================

extern "C" void kernel_launch(void* const* d_in, const int* in_sizes, int n_in,
                              void* d_out, int out_size, void* d_ws, size_t ws_size,
                              hipStream_t stream) {
    const float* x    = (const float*)d_in[0];
    const float* keys = (const float*)d_in[1];
    const float* V    = (const float*)d_in[2];
    float* out = (float*)d_out;

    // ws layout
    const size_t off_xn2 = 0;            // 4096 f32
    const size_t off_kn2 = 16384;        // 50048 f32
    const size_t off_xbf = 216576;       // 4096x64 bf16
    const size_t off_kbf = 740864;       // 50048x64 bf16
    const size_t off_vt  = 7147008;      // 1024x50048 bf16
    const size_t off_p   = 109645312;    // partial(s) f32
    const size_t PBYTES  = (size_t)B_ROWS * NCOL * 4;      // 16.384 MB
    const size_t total_atomic = off_p + PBYTES;            // ~126 MB
    const size_t total_parts  = off_p + 4 * PBYTES;        // ~175 MB

    if (ws_size >= total_atomic) {
        char* ws = (char*)d_ws;
        float* xn2 = (float*)(ws + off_xn2);
        float* kn2 = (float*)(ws + off_kn2);
        u16* x_bf  = (u16*)(ws + off_xbf);
        u16* k_bf  = (u16*)(ws + off_kbf);
        u16* vt    = (u16*)(ws + off_vt);
        float* partial = (float*)(ws + off_p);
        const int use_parts = (ws_size >= total_parts);

        prep_x_kernel<<<B_ROWS / 4, 256, 0, stream>>>(x, x_bf, xn2);
        prep_keys_kernel<<<DPAD / 4, 256, 0, stream>>>(keys, k_bf, kn2);
        prep_v_kernel<<<dim3(DPAD / 64, NPAD / 64), 256, 0, stream>>>(V, vt);
        if (!use_parts)
            zero_kernel<<<1024, 256, 0, stream>>>((float4*)partial,
                                                  (int)(PBYTES / 16));
        varkeys_mfma2_kernel<<<dim3(8, 16, 4), 256, 0, stream>>>(
            x_bf, k_bf, vt, xn2, kn2, partial, use_parts ? 0 : 1);
        finish_kernel<<<B_ROWS, 256, 0, stream>>>(partial, out, use_parts ? 4 : 1);
    } else {
        float* xn = (float*)d_ws;
        float* kn = xn + B_ROWS;
        row_norm2_kernel<<<B_ROWS / 4, 256, 0, stream>>>(x, xn, B_ROWS);
        row_norm2_kernel<<<D_KEYS / 4 + 1, 256, 0, stream>>>(keys, kn, D_KEYS);
        dim3 grid(4, B_ROWS / BT);
        varkeys_main_kernel<<<grid, 256, 0, stream>>>(x, keys, V, xn, kn, out);
        normalize_kernel<<<B_ROWS, 256, 0, stream>>>(out);
    }
}

// Round 5
// 1245.349 us; speedup vs baseline: 1.3305x; 1.3305x over previous
//
#include <hip/hip_runtime.h>
#include <hip/hip_bf16.h>

typedef __attribute__((ext_vector_type(8))) short short8;
typedef __attribute__((ext_vector_type(16))) float f32x16;
typedef __attribute__((ext_vector_type(4))) unsigned int u32x4;
typedef unsigned short u16;
typedef unsigned int u32;

#define B_ROWS 4096
#define D_KEYS 50000
#define DPAD   50048
#define KDIM   64
#define NCOL   1000
#define NPAD   1024
#define SCALEF 300000.0f
#define EPSF   1e-4f
#define NCHUNKS 782          // DPAD/64
#define NEG2S  (-2.0f / SCALEF)
#define DZ     4

// ---------------- helpers ----------------

__device__ __forceinline__ u16 f2bf(float f) {          // RNE float->bf16
    u32 u = __builtin_bit_cast(u32, f);
    u = (u + 0x7FFFu + ((u >> 16) & 1u)) >> 16;
    return (u16)u;
}

__device__ __forceinline__ u32 pack2(float a, float b) { // 2xf32 -> packed bf16x2
    __hip_bfloat162 r = __float22bfloat162_rn(make_float2(a, b));
    u32 pk;
    __builtin_memcpy(&pk, &r, 4);
    return pk;
}

__device__ __forceinline__ void glds16(const void* g, void* l) {
    __builtin_amdgcn_global_load_lds(
        (const __attribute__((address_space(1))) u32*)(uintptr_t)g,
        (__attribute__((address_space(3))) u32*)(uintptr_t)l, 16, 0, 0);
}

// ---------------- pre-pass kernels ----------------

__global__ void prep_x_kernel(const float* __restrict__ x,
                              u16* __restrict__ x_bf, float* __restrict__ xn2) {
    int row = (blockIdx.x * blockDim.x + threadIdx.x) >> 6;
    int lane = threadIdx.x & 63;
    if (row >= B_ROWS) return;
    float v = x[(size_t)row * KDIM + lane];
    x_bf[(size_t)row * KDIM + lane] = f2bf(v);
    float s = v * v;
    #pragma unroll
    for (int off = 32; off > 0; off >>= 1) s += __shfl_down(s, off, 64);
    if (lane == 0) xn2[row] = s * (1.0f / SCALEF);
}

__global__ void prep_keys_kernel(const float* __restrict__ keys,
                                 u16* __restrict__ keys_bf, float* __restrict__ kn2) {
    int row = (blockIdx.x * blockDim.x + threadIdx.x) >> 6;
    int lane = threadIdx.x & 63;
    if (row >= DPAD) return;
    float v = (row < D_KEYS) ? keys[(size_t)row * KDIM + lane] : 0.f;
    keys_bf[(size_t)row * KDIM + lane] = f2bf(v);
    float s = v * v;
    #pragma unroll
    for (int off = 32; off > 0; off >>= 1) s += __shfl_down(s, off, 64);
    if (lane == 0) kn2[row] = s * (1.0f / SCALEF) + EPSF;
}

// V (50000x1000 f32) -> Vt (1024x50048 bf16, d contiguous), zero-padded
__global__ void prep_v_kernel(const float* __restrict__ V, u16* __restrict__ vt) {
    __shared__ float tile[64][65];
    const int d0 = blockIdx.x * 64;
    const int n0 = blockIdx.y * 64;
    const int t = threadIdx.x;
    #pragma unroll
    for (int p = 0; p < 16; p++) {
        int idx = p * 256 + t;
        int di = idx >> 6, nj = idx & 63;
        int d = d0 + di, n = n0 + nj;
        tile[di][nj] = (d < D_KEYS && n < NCOL) ? V[(size_t)d * NCOL + n] : 0.f;
    }
    __syncthreads();
    #pragma unroll
    for (int p = 0; p < 8; p++) {
        int idx = p * 256 + t;
        int ni = idx >> 5, dp = idx & 31;          // d-pair
        u32 pk = pack2(tile[2 * dp][ni], tile[2 * dp + 1][ni]);
        *(u32*)&vt[(size_t)(n0 + ni) * DPAD + d0 + 2 * dp] = pk;
    }
}

__global__ void zero_kernel(float4* __restrict__ p, int n4) {
    for (int i = blockIdx.x * 256 + threadIdx.x; i < n4; i += gridDim.x * 256)
        p[i] = make_float4(0.f, 0.f, 0.f, 0.f);
}

// ---------------- main MFMA kernel ----------------
// grid (8 n-tiles, 32 b-tiles, DZ d-splits), 256 threads (4 waves)
// BM=128 (wave owns 32 b-rows), BN=128 (4 n-tiles of 32), D-chunk 64.
// Scores C-layout -> PV A-layout via __shfl_xor(32) (no ker LDS round-trip).
__global__ __launch_bounds__(256, 3)
void varkeys_mfma3_kernel(const u16* __restrict__ x_bf,
                          const u16* __restrict__ keys_bf,
                          const u16* __restrict__ vt_bf,
                          const float* __restrict__ xn2,
                          const float* __restrict__ kn2,
                          float* __restrict__ partial,
                          int atomic_mode) {
    __shared__ alignas(16) u16 keys_lds[64 * 64];    // [d][k], 16B-swizzled
    __shared__ alignas(16) u16 v_lds[128 * 64];      // [n][d], 16B-swizzled
    __shared__ alignas(16) float kn_lds[64];

    const int t = threadIdx.x;
    const int w = t >> 6;
    const int lane = t & 63;
    const int half = lane >> 5;            // h
    const int l31 = lane & 31;

    const int n0 = blockIdx.x * 128;
    const int b0 = blockIdx.y * 128;
    const int bz = blockIdx.z;
    const int c_begin = (bz * NCHUNKS) / DZ;
    const int c_end = ((bz + 1) * NCHUNKS) / DZ;

    const int bl = 32 * w + l31;           // wave's own b-row (scores n-col & PV m-row)
    const float xnv = xn2[b0 + bl];

    // x fragments (scores B operand) pinned in VGPRs
    short8 xfrag[4];
    #pragma unroll
    for (int kk = 0; kk < 4; kk++)
        xfrag[kk] = *(const short8*)(x_bf + (size_t)(b0 + bl) * KDIM + kk * 16 + half * 8);

    f32x16 acc[4];
    #pragma unroll
    for (int nt = 0; nt < 4; nt++)
        #pragma unroll
        for (int i = 0; i < 16; i++) acc[nt][i] = 0.f;

    const int srow = lane >> 3;
    const int cg = (lane & 7) ^ srow;      // swizzled 16B chunk for staging

    for (int c = c_begin; c < c_end; c++) {
        const int d0 = c * 64;

        // ---- stage keys (8KB) + Vt (16KB), 16B-swizzled direct-to-LDS ----
        #pragma unroll
        for (int q = 0; q < 2; q++) {
            int i = w * 2 + q;
            glds16(keys_bf + (size_t)(d0 + 8 * i + srow) * KDIM + cg * 8,
                   &keys_lds[i * 512]);
        }
        #pragma unroll
        for (int q = 0; q < 4; q++) {
            int i = w * 4 + q;
            glds16(vt_bf + (size_t)(n0 + 8 * i + srow) * DPAD + d0 + cg * 8,
                   &v_lds[i * 512]);
        }
        if (t < 16) *(float4*)&kn_lds[t * 4] = *(const float4*)&kn2[d0 + t * 4];
        __syncthreads();

        const bool tail = (d0 + 64 > D_KEYS);

        #pragma unroll
        for (int dt = 0; dt < 2; dt++) {
            // ---- scores MFMA: m=d (A=keys), n=b (B=x) ----
            f32x16 s;
            #pragma unroll
            for (int i = 0; i < 16; i++) s[i] = 0.f;
            const int dl = dt * 32 + l31;
            #pragma unroll
            for (int kk = 0; kk < 4; kk++) {
                int cidx = kk * 2 + half;
                short8 af = *(const short8*)&keys_lds[dl * 64 + ((cidx ^ (dl & 7)) * 8)];
                s = __builtin_amdgcn_mfma_f32_32x32x16_bf16(af, xfrag[kk], s, 0, 0, 0);
            }
            // ---- epilogue: dist -> rcp -> bf16 pairs P[m][2] (own d-quads) ----
            // lane's s[r] = ker[d = dt*32 + (r&3)+8*(r>>2)+4*half][b = own bl]
            u32 P[4][2];
            #pragma unroll
            for (int m = 0; m < 4; m++) {
                float kv[4];
                #pragma unroll
                for (int j = 0; j < 4; j++) {
                    int r = 4 * m + j;
                    int dloc = dt * 32 + 8 * m + 4 * half + j;
                    float dist = fmaf(s[r], NEG2S, kn_lds[dloc] + xnv);
                    kv[j] = __builtin_amdgcn_rcpf(dist);
                }
                if (tail) {
                    #pragma unroll
                    for (int j = 0; j < 4; j++)
                        if (d0 + dt * 32 + 8 * m + 4 * half + j >= D_KEYS) kv[j] = 0.f;
                }
                P[m][0] = pack2(kv[0], kv[1]);
                P[m][1] = pack2(kv[2], kv[3]);
            }
            // ---- C->A transform via half-wave exchange + PV MFMA ----
            #pragma unroll
            for (int q = 0; q < 2; q++) {
                // send own quad the partner needs; receive partner's
                u32 s0 = half ? P[2 * q][0] : P[2 * q + 1][0];
                u32 s1 = half ? P[2 * q][1] : P[2 * q + 1][1];
                u32 r0 = __shfl_xor((int)s0, 32, 64);
                u32 r1 = __shfl_xor((int)s1, 32, 64);
                u32x4 fr;
                fr.x = half ? r0 : P[2 * q][0];
                fr.y = half ? r1 : P[2 * q][1];
                fr.z = half ? P[2 * q + 1][0] : r0;
                fr.w = half ? P[2 * q + 1][1] : r1;
                short8 kfrag = __builtin_bit_cast(short8, fr);
                const int kk = dt * 2 + q;
                const int cidx = kk * 2 + half;
                #pragma unroll
                for (int nt = 0; nt < 4; nt++) {
                    int nl = nt * 32 + l31;
                    short8 vf = *(const short8*)&v_lds[nl * 64 + ((cidx ^ (nl & 7)) * 8)];
                    acc[nt] = __builtin_amdgcn_mfma_f32_32x32x16_bf16(kfrag, vf, acc[nt], 0, 0, 0);
                }
            }
        }
        __syncthreads();   // protect keys_lds/v_lds before next stage
    }

    // ---- output: per-dz partial buffer, or atomicAdd ----
    float* pout = atomic_mode ? partial
                              : partial + (size_t)bz * B_ROWS * NCOL;
    #pragma unroll
    for (int nt = 0; nt < 4; nt++) {
        int n = n0 + nt * 32 + l31;
        if (n < NCOL) {
            #pragma unroll
            for (int r = 0; r < 16; r++) {
                int brow = b0 + 32 * w + (r & 3) + 8 * (r >> 2) + 4 * half;
                if (atomic_mode)
                    atomicAdd(&pout[(size_t)brow * NCOL + n], acc[nt][r]);
                else
                    pout[(size_t)brow * NCOL + n] = acc[nt][r];
            }
        }
    }
}

// sum pcount partials, row-normalize
__global__ void finish_kernel(const float* __restrict__ partial, float* __restrict__ out,
                              int pcount) {
    const int b = blockIdx.x;
    const int t = threadIdx.x;
    float s = 0.f;
    for (int n = t; n < NCOL; n += 256) {
        float v = 0.f;
        for (int p = 0; p < pcount; p++)
            v += partial[(size_t)p * B_ROWS * NCOL + (size_t)b * NCOL + n];
        s += v;
    }
    __shared__ float red[4];
    #pragma unroll
    for (int off = 32; off > 0; off >>= 1) s += __shfl_down(s, off, 64);
    if ((t & 63) == 0) red[t >> 6] = s;
    __syncthreads();
    float inv = 1.0f / (red[0] + red[1] + red[2] + red[3]);
    for (int n = t; n < NCOL; n += 256) {
        float v = 0.f;
        for (int p = 0; p < pcount; p++)
            v += partial[(size_t)p * B_ROWS * NCOL + (size_t)b * NCOL + n];
        out[(size_t)b * NCOL + n] = v * inv;
    }
}

// ================= fallback fp32 path (round-1, known-correct) =================

__global__ void row_norm2_kernel(const float* __restrict__ a,
                                 float* __restrict__ out, int rows) {
    int wave = (blockIdx.x * blockDim.x + threadIdx.x) >> 6;
    int lane = threadIdx.x & 63;
    if (wave >= rows) return;
    float v = a[(size_t)wave * KDIM + lane];
    float s = v * v;
    #pragma unroll
    for (int off = 32; off > 0; off >>= 1) s += __shfl_down(s, off, 64);
    if (lane == 0) out[wave] = s;
}

#define DC 64
#define BT 64
#define NT 256

__global__ __launch_bounds__(256, 1)
void varkeys_main_kernel(const float* __restrict__ x,
                         const float* __restrict__ keys,
                         const float* __restrict__ V,
                         const float* __restrict__ xn,
                         const float* __restrict__ kn,
                         float* __restrict__ out) {
    __shared__ float x_lds[BT][68];
    __shared__ float keys_lds[DC][68];
    __shared__ float ker_lds[DC][65];
    __shared__ float xn_lds[BT];
    __shared__ float kn_lds[DC];
    const int t = threadIdx.x;
    const int n0 = blockIdx.x * NT;
    const int b0 = blockIdx.y * BT;
    for (int q = t; q < BT * 16; q += 256) {
        int row = q >> 4, c4 = q & 15;
        float4 v = *(const float4*)(x + (size_t)(b0 + row) * KDIM + c4 * 4);
        *(float4*)&x_lds[row][c4 * 4] = v;
    }
    if (t < BT) xn_lds[t] = xn[b0 + t];
    const int tn = t & 63;
    const int tb = t >> 6;
    const int tb16 = tb * 16;
    const int n4 = n0 + 4 * tn;
    const bool nvalid = (n4 < NCOL);
    float4 acc[16];
    #pragma unroll
    for (int j = 0; j < 16; j++) acc[j] = make_float4(0.f, 0.f, 0.f, 0.f);
    const int td = t & 15;
    const int tq = t >> 4;
    for (int d0 = 0; d0 < D_KEYS; d0 += DC) {
        const int dlim = min(DC, D_KEYS - d0);
        for (int q = t; q < DC * 16; q += 256) {
            int row = q >> 4, c4 = q & 15;
            if (d0 + row < D_KEYS) {
                float4 v = *(const float4*)(keys + (size_t)(d0 + row) * KDIM + c4 * 4);
                *(float4*)&keys_lds[row][c4 * 4] = v;
            }
        }
        if (t < DC) kn_lds[t] = (d0 + t < D_KEYS) ? kn[d0 + t] : 0.f;
        __syncthreads();
        {
            float4 s[4][4];
            #pragma unroll
            for (int i = 0; i < 4; i++)
                #pragma unroll
                for (int j = 0; j < 4; j++) s[i][j] = make_float4(0.f, 0.f, 0.f, 0.f);
            #pragma unroll
            for (int k4 = 0; k4 < 16; k4++) {
                float4 kv[4], xv[4];
                #pragma unroll
                for (int i = 0; i < 4; i++) kv[i] = *(const float4*)&keys_lds[td + 16 * i][k4 * 4];
                #pragma unroll
                for (int j = 0; j < 4; j++) xv[j] = *(const float4*)&x_lds[tq + 16 * j][k4 * 4];
                #pragma unroll
                for (int i = 0; i < 4; i++)
                    #pragma unroll
                    for (int j = 0; j < 4; j++) {
                        s[i][j].x += kv[i].x * xv[j].x;
                        s[i][j].y += kv[i].y * xv[j].y;
                        s[i][j].z += kv[i].z * xv[j].z;
                        s[i][j].w += kv[i].w * xv[j].w;
                    }
            }
            #pragma unroll
            for (int i = 0; i < 4; i++)
                #pragma unroll
                for (int j = 0; j < 4; j++) {
                    int d = td + 16 * i, bb = tq + 16 * j;
                    float dot = s[i][j].x + s[i][j].y + s[i][j].z + s[i][j].w;
                    float dist = (kn_lds[d] - 2.0f * dot + xn_lds[bb]) * (1.0f / SCALEF) + EPSF;
                    ker_lds[d][bb] = 1.0f / dist;
                }
        }
        __syncthreads();
        if (nvalid) {
            const float* vp = V + (size_t)d0 * NCOL + n4;
            for (int d = 0; d < dlim; d += 4) {
                float4 v0 = *(const float4*)(vp + (size_t)(d + 0) * NCOL);
                float4 v1 = *(const float4*)(vp + (size_t)(d + 1) * NCOL);
                float4 v2 = *(const float4*)(vp + (size_t)(d + 2) * NCOL);
                float4 v3 = *(const float4*)(vp + (size_t)(d + 3) * NCOL);
                #pragma unroll
                for (int j = 0; j < 16; j++) {
                    float k0 = ker_lds[d + 0][tb16 + j];
                    float k1 = ker_lds[d + 1][tb16 + j];
                    float k2 = ker_lds[d + 2][tb16 + j];
                    float k3 = ker_lds[d + 3][tb16 + j];
                    acc[j].x += k0 * v0.x + k1 * v1.x + k2 * v2.x + k3 * v3.x;
                    acc[j].y += k0 * v0.y + k1 * v1.y + k2 * v2.y + k3 * v3.y;
                    acc[j].z += k0 * v0.z + k1 * v1.z + k2 * v2.z + k3 * v3.z;
                    acc[j].w += k0 * v0.w + k1 * v1.w + k2 * v2.w + k3 * v3.w;
                }
            }
        }
    }
    if (nvalid) {
        #pragma unroll
        for (int j = 0; j < 16; j++) {
            int b = b0 + tb16 + j;
            *(float4*)(out + (size_t)b * NCOL + n4) = acc[j];
        }
    }
}

__global__ void normalize_kernel(float* __restrict__ out) {
    const int b = blockIdx.x;
    float* row = out + (size_t)b * NCOL;
    const int t = threadIdx.x;
    float s = 0.f;
    for (int n = t; n < NCOL; n += 256) s += row[n];
    __shared__ float red[4];
    #pragma unroll
    for (int off = 32; off > 0; off >>= 1) s += __shfl_down(s, off, 64);
    if ((t & 63) == 0) red[t >> 6] = s;
    __syncthreads();
    float inv = 1.0f / (red[0] + red[1] + red[2] + red[3]);
    for (int n = t; n < NCOL; n += 256) row[n] *= inv;
}

// ================= launch =================

extern "C" void kernel_launch(void* const* d_in, const int* in_sizes, int n_in,
                              void* d_out, int out_size, void* d_ws, size_t ws_size,
                              hipStream_t stream) {
    const float* x    = (const float*)d_in[0];
    const float* keys = (const float*)d_in[1];
    const float* V    = (const float*)d_in[2];
    float* out = (float*)d_out;

    // ws layout
    const size_t off_xn2 = 0;            // 4096 f32
    const size_t off_kn2 = 16384;        // 50048 f32
    const size_t off_xbf = 216576;       // 4096x64 bf16
    const size_t off_kbf = 740864;       // 50048x64 bf16
    const size_t off_vt  = 7147008;      // 1024x50048 bf16
    const size_t off_p   = 109645312;    // partial(s) f32
    const size_t PBYTES  = (size_t)B_ROWS * NCOL * 4;      // 16.384 MB
    const size_t total_atomic = off_p + PBYTES;            // ~126 MB
    const size_t total_parts  = off_p + DZ * PBYTES;       // ~175 MB

    if (ws_size >= total_atomic) {
        char* ws = (char*)d_ws;
        float* xn2 = (float*)(ws + off_xn2);
        float* kn2 = (float*)(ws + off_kn2);
        u16* x_bf  = (u16*)(ws + off_xbf);
        u16* k_bf  = (u16*)(ws + off_kbf);
        u16* vt    = (u16*)(ws + off_vt);
        float* partial = (float*)(ws + off_p);
        const int use_parts = (ws_size >= total_parts);

        prep_x_kernel<<<B_ROWS / 4, 256, 0, stream>>>(x, x_bf, xn2);
        prep_keys_kernel<<<DPAD / 4, 256, 0, stream>>>(keys, k_bf, kn2);
        prep_v_kernel<<<dim3(DPAD / 64, NPAD / 64), 256, 0, stream>>>(V, vt);
        if (!use_parts)
            zero_kernel<<<1024, 256, 0, stream>>>((float4*)partial,
                                                  (int)(PBYTES / 16));
        varkeys_mfma3_kernel<<<dim3(8, 32, DZ), 256, 0, stream>>>(
            x_bf, k_bf, vt, xn2, kn2, partial, use_parts ? 0 : 1);
        finish_kernel<<<B_ROWS, 256, 0, stream>>>(partial, out, use_parts ? DZ : 1);
    } else {
        float* xn = (float*)d_ws;
        float* kn = xn + B_ROWS;
        row_norm2_kernel<<<B_ROWS / 4, 256, 0, stream>>>(x, xn, B_ROWS);
        row_norm2_kernel<<<D_KEYS / 4 + 1, 256, 0, stream>>>(keys, kn, D_KEYS);
        dim3 grid(4, B_ROWS / BT);
        varkeys_main_kernel<<<grid, 256, 0, stream>>>(x, keys, V, xn, kn, out);
        normalize_kernel<<<B_ROWS, 256, 0, stream>>>(out);
    }
}